// Round 3
// baseline (102.406 us; speedup 1.0000x reference)
//
#include <hip/hip_runtime.h>

// DWA_CNN: B=32, T=2048, C=128, K=3, F=8, P=2046
// v3: register-tiled phase-1 (8x6 acc per lane, 4-way K-split across waves,
//     ds_add_f32 combine), coalesced x staging with register prefetch,
//     norms fused into staging via quad-shuffle reduce.

#define TT   126          // outputs per block; rows = 128
#define RWS  128          // G rows per block
#define XSTR 17           // x chunk row stride (16 c + 1 pad)
#define GSTR 27           // G row stride (25 used, odd -> spread banks)
#define WSTR 132          // Wt row stride (128 + 4)
#define BIGV 1234567891011.0f

// Backtrace step for compile-time state (I,J), exact jnp.argmin tie semantics.
#define TRACE_CASE(I, J)                                                      \
  case (((I) << 2) | (J)): {                                                  \
    const float ca = cost[(I)-1][(J)-1];                                      \
    const float cb = cost[(I)][(J)-1];                                        \
    const float cc = cost[(I)-1][(J)];                                        \
    const int m = (ca <= cb) ? ((ca <= cc) ? 0 : 2) : ((cb <= cc) ? 1 : 2);   \
    const int i2 = (I) - ((m == 1) ? 0 : 1);                                  \
    const int j2 = (J) - ((m == 2) ? 0 : 1);                                  \
    const bool nxt = (i2 > 0) && (j2 > 0);                                    \
    if (nxt) {                                                                \
      const float add =                                                       \
          (m == 0) ? dots[((I) >= 2) ? (I)-2 : 0][((J) >= 2) ? (J)-2 : 0]     \
        : (m == 1) ? dots[(I)-1][((J) >= 2) ? (J)-2 : 0]                      \
                   : dots[((I) >= 2) ? (I)-2 : 0][(J)-1];                     \
      acc += add;                                                             \
    }                                                                         \
    st = (i2 << 2) | j2;                                                      \
    active = nxt;                                                             \
  } break;

#define LOADC(CB)                                                             \
  _Pragma("unroll")                                                           \
  for (int pp = 0; pp < 8; ++pp) {                                            \
    const int t = p0 + pp * 16 + srow;                                        \
    if (t < T) stg[pp] = *(const float4*)&x[((size_t)b * T + t) * C + (CB) + scol]; \
    else stg[pp] = make_float4(0.f, 0.f, 0.f, 0.f);                           \
  }

#define WRITEC()                                                              \
  _Pragma("unroll")                                                           \
  for (int pp = 0; pp < 8; ++pp) {                                            \
    const int r = pp * 16 + srow;                                             \
    *(float4*)&Xb[r * XSTR + scol] = stg[pp];                                 \
    float ns = fmaf(stg[pp].x, stg[pp].x, fmaf(stg[pp].y, stg[pp].y,          \
               fmaf(stg[pp].z, stg[pp].z, stg[pp].w * stg[pp].w)));           \
    ns += __shfl_xor(ns, 1);                                                  \
    ns += __shfl_xor(ns, 2);                                                  \
    if ((lane & 3) == 0) atomicAdd(&G[r * GSTR + 24], ns);                    \
  }

#define COMPUTEC(CB)                                                          \
  _Pragma("unroll")                                                           \
  for (int c4 = 0; c4 < 16; c4 += 4) {                                        \
    float4 wf[6], xr[8];                                                      \
    _Pragma("unroll")                                                         \
    for (int cc = 0; cc < 6; ++cc)                                            \
      wf[cc] = *(const float4*)&Wt[(cg * 6 + cc) * WSTR + (CB) + c4];         \
    _Pragma("unroll")                                                         \
    for (int rr = 0; rr < 8; ++rr)                                            \
      xr[rr] = *(const float4*)&Xb[(rg + 16 * rr) * XSTR + c4];               \
    _Pragma("unroll")                                                         \
    for (int rr = 0; rr < 8; ++rr) {                                          \
      _Pragma("unroll")                                                       \
      for (int cc = 0; cc < 6; ++cc) {                                        \
        accp[rr][cc] = fmaf(xr[rr].x, wf[cc].x, accp[rr][cc]);                \
        accp[rr][cc] = fmaf(xr[rr].y, wf[cc].y, accp[rr][cc]);                \
        accp[rr][cc] = fmaf(xr[rr].z, wf[cc].z, accp[rr][cc]);                \
        accp[rr][cc] = fmaf(xr[rr].w, wf[cc].w, accp[rr][cc]);                \
      }                                                                       \
    }                                                                         \
  }

__global__ __launch_bounds__(256, 2) void dwa_cnn_kernel(
    const float* __restrict__ x, const float* __restrict__ w,
    const float* __restrict__ bias, float* __restrict__ out)
{
  constexpr int T = 2048, C = 128, P = 2046;

  __shared__ float Wt[24 * WSTR];        // transposed w: Wt[q][c], q=k*8+f
  __shared__ float Xw[4][RWS * XSTR];    // per-wave x chunk [row][16c]
  __shared__ float G[RWS * GSTR];        // [row][0..23]=dots, [24]=|x|^2
  __shared__ float WN[24];
  __shared__ float BI[8];

  const int tid  = threadIdx.x;
  const int b    = blockIdx.y;
  const int p0   = blockIdx.x * TT;
  const int wave = tid >> 6;
  const int lane = tid & 63;

  // ---- stage Wt (transposed), zero G, bias ----
  for (int i = tid; i < 3072; i += 256) {
    const int q = i >> 7, c = i & 127;
    const int k = q >> 3, f = q & 7;
    Wt[q * WSTR + c] = w[(k * C + c) * 8 + f];
  }
  for (int i = tid; i < RWS * GSTR; i += 256) G[i] = 0.f;
  if (tid < 8) BI[tid] = bias[tid];
  __syncthreads();

  // filter norms (threads 0..23, overlapped with other waves' phase 1)
  if (tid < 24) {
    float s = 0.f;
    for (int c = 0; c < C; ++c) { const float v = Wt[tid * WSTR + c]; s = fmaf(v, v, s); }
    WN[tid] = s;
  }

  // ---- phase 1: wave = c-quarter [cq, cq+32); lane = (rg, cg) tile 8x6 ----
  const int cq   = wave * 32;
  const int rg   = lane >> 2, cg = lane & 3;
  const int srow = lane >> 2, scol = (lane & 3) * 4;
  float* Xb = Xw[wave];

  float accp[8][6];
  #pragma unroll
  for (int rr = 0; rr < 8; ++rr)
    #pragma unroll
    for (int cc = 0; cc < 6; ++cc) accp[rr][cc] = 0.f;

  float4 stg[8];
  LOADC(cq);            // prefetch chunk 0
  WRITEC();             // LDS write + norm partials (chunk 0)
  LOADC(cq + 16);       // prefetch chunk 1 (latency hidden under compute 0)
  COMPUTEC(cq);
  WRITEC();             // LDS write + norm partials (chunk 1)
  COMPUTEC(cq + 16);

  // combine K-split partials into G
  #pragma unroll
  for (int rr = 0; rr < 8; ++rr)
    #pragma unroll
    for (int cc = 0; cc < 6; ++cc)
      atomicAdd(&G[(rg + 16 * rr) * GSTR + cg * 6 + cc], accp[rr][cc]);

  __syncthreads();

  // ---- phase 2: one (p, f) output per thread-iteration ----
  for (int o = tid; o < TT * 8; o += 256) {
    const int pl = o >> 3, f = o & 7;
    const int p  = p0 + pl;

    float xn[3], dots[3][3];
    #pragma unroll
    for (int i = 0; i < 3; ++i) {
      xn[i] = G[(pl + i) * GSTR + 24];
      #pragma unroll
      for (int j = 0; j < 3; ++j) dots[i][j] = G[(pl + i) * GSTR + j * 8 + f];
    }

    float D[3][3];
    #pragma unroll
    for (int i = 0; i < 3; ++i) {
      #pragma unroll
      for (int j = 0; j < 3; ++j) {
        const float sq = xn[i] + WN[j * 8 + f] - 2.f * dots[i][j];
        D[i][j] = sqrtf(fmaxf(sq, 0.f));
      }
    }

    float cost[4][4];
    cost[0][0] = 0.f;  cost[0][1] = BIGV; cost[0][2] = BIGV; cost[0][3] = BIGV;
    #pragma unroll
    for (int i = 1; i <= 3; ++i) {
      cost[i][0] = BIGV;
      #pragma unroll
      for (int j = 1; j <= 3; ++j) {
        cost[i][j] = D[i-1][j-1] +
            fminf(fminf(cost[i][j-1], cost[i-1][j-1]), cost[i-1][j]);
      }
    }

    float acc2 = dots[2][2];
    {
      float acc = acc2;
      int st = (3 << 2) | 3;
      bool active = true;
      #pragma unroll 1
      for (int s = 0; s < 5; ++s) {
        if (!active) break;
        switch (st) {
          TRACE_CASE(1, 1)
          TRACE_CASE(1, 2)
          TRACE_CASE(1, 3)
          TRACE_CASE(2, 1)
          TRACE_CASE(2, 2)
          TRACE_CASE(2, 3)
          TRACE_CASE(3, 1)
          TRACE_CASE(3, 2)
          TRACE_CASE(3, 3)
          default: active = false; break;
        }
      }
      acc2 = acc;
    }

    if (p < P) out[((size_t)b * P + p) * 8 + f] = fmaxf(acc2 + BI[f], 0.f);
  }
}

extern "C" void kernel_launch(void* const* d_in, const int* in_sizes, int n_in,
                              void* d_out, int out_size, void* d_ws, size_t ws_size,
                              hipStream_t stream) {
  const float* x    = (const float*)d_in[0];
  const float* w    = (const float*)d_in[1];
  const float* bias = (const float*)d_in[2];
  float* out        = (float*)d_out;

  dim3 grid(17, 32);  // ceil(2046/126) x B
  dwa_cnn_kernel<<<grid, 256, 0, stream>>>(x, w, bias, out);
}

// Round 4
// 16.625 us; speedup vs baseline: 6.1596x; 6.1596x over previous
//
#include <hip/hip_runtime.h>

// DWA_CNN: B=32, T=2048, C=128, K=3, F=8, P=2046
// v4: bf16 MFMA for the G-GEMM (numerically safe: DTW decision margins ~11,
//     bf16 dot error ~0.01, threshold 0.1925). Coalesced x->LDS bf16 staging
//     with XOR swizzle, 16x16x32 MFMA, no atomics, ~60 VGPR. Phase 2 = v2.

#define TT   62
#define RWS  64
#define GSTR 27
#define BIGV 1234567891011.0f

typedef __attribute__((ext_vector_type(8))) short short8v;
typedef __attribute__((ext_vector_type(4))) float f32x4;

static __device__ inline unsigned short f2bf(float f) {
  unsigned u = __float_as_uint(f);
  u = (u + 0x7FFF + ((u >> 16) & 1)) >> 16;   // RNE
  return (unsigned short)u;
}
static __device__ inline float bf2f(unsigned short h) {
  return __uint_as_float(((unsigned)h) << 16);
}

#define TRACE_CASE(I, J)                                                      \
  case (((I) << 2) | (J)): {                                                  \
    const float ca = cost[(I)-1][(J)-1];                                      \
    const float cb = cost[(I)][(J)-1];                                        \
    const float cc = cost[(I)-1][(J)];                                        \
    const int m = (ca <= cb) ? ((ca <= cc) ? 0 : 2) : ((cb <= cc) ? 1 : 2);   \
    const int i2 = (I) - ((m == 1) ? 0 : 1);                                  \
    const int j2 = (J) - ((m == 2) ? 0 : 1);                                  \
    const bool nxt = (i2 > 0) && (j2 > 0);                                    \
    if (nxt) {                                                                \
      const float add =                                                       \
          (m == 0) ? dots[((I) >= 2) ? (I)-2 : 0][((J) >= 2) ? (J)-2 : 0]     \
        : (m == 1) ? dots[(I)-1][((J) >= 2) ? (J)-2 : 0]                      \
                   : dots[((I) >= 2) ? (I)-2 : 0][(J)-1];                     \
      acc += add;                                                             \
    }                                                                         \
    st = (i2 << 2) | j2;                                                      \
    active = nxt;                                                             \
  } break;

__global__ __launch_bounds__(256, 4) void dwa_cnn_kernel(
    const float* __restrict__ x, const float* __restrict__ w,
    const float* __restrict__ bias, float* __restrict__ out)
{
  constexpr int T = 2048, C = 128, P = 2046;

  // bf16 tiles, XOR-swizzled: element (r, c) at r*128 + ((c>>3)^(r&7))*8 + (c&7)
  __shared__ unsigned short Xs[RWS * 128];   // 16 KB
  __shared__ unsigned short Wb[32 * 128];    // 8 KB (q=24..31 zero)
  __shared__ float G[RWS * GSTR];            // 6.9 KB: [row][0..23]=dots, [24]=|x|^2
  __shared__ float WN[24];
  __shared__ float BI[8];

  const int tid  = threadIdx.x;
  const int b    = blockIdx.y;
  const int p0   = blockIdx.x * TT;          // 33*62 = 2046 exact; rows p0..p0+63 <= 2047
  const int wave = tid >> 6;
  const int lane = tid & 63;

  // ---- stage x -> Xs (bf16, swizzled, coalesced dwordx4 reads) ----
  {
    const int qd = tid & 31, r0 = tid >> 5;  // qd = float4-quad within row
    #pragma unroll
    for (int it = 0; it < 8; ++it) {
      const int row = r0 + it * 8;
      const float4 xv = *(const float4*)&x[((size_t)b * T + p0 + row) * C + qd * 4];
      ushort4 pk;
      pk.x = f2bf(xv.x); pk.y = f2bf(xv.y); pk.z = f2bf(xv.z); pk.w = f2bf(xv.w);
      *(ushort4*)&Xs[row * 128 + (((qd >> 1) ^ (row & 7)) << 3) + ((qd & 1) << 2)] = pk;
    }
  }

  // ---- stage w -> Wb (bf16, swizzled), zero pad rows 24..31 ----
  #pragma unroll
  for (int j = 0; j < 12; ++j) {
    const int i = tid + j * 256;             // i = k*1024 + c*8 + f
    const int k = i >> 10, c = (i >> 3) & 127, f = i & 7;
    const int q = k * 8 + f;
    Wb[q * 128 + (((c >> 3) ^ (q & 7)) << 3) + (c & 7)] = f2bf(w[i]);
  }
  #pragma unroll
  for (int j = 0; j < 4; ++j) {
    const int i = tid + j * 256;
    const int q = 24 + (i >> 7), c = i & 127;
    Wb[q * 128 + (((c >> 3) ^ (q & 7)) << 3) + (c & 7)] = 0;
  }

  // ---- WN: fp32 filter norms from global w (threads 0..95) ----
  if (tid < 96) {
    const int q = tid >> 2, c0 = (tid & 3) * 32;
    const int k = q >> 3, f = q & 7;
    float s = 0.f;
    #pragma unroll 8
    for (int c = c0; c < c0 + 32; ++c) {
      const float v = w[k * 1024 + c * 8 + f];
      s = fmaf(v, v, s);
    }
    s += __shfl_xor(s, 1);
    s += __shfl_xor(s, 2);
    if ((tid & 3) == 0) WN[q] = s;
  }
  if (tid < 8) BI[tid] = bias[tid];
  __syncthreads();

  // ---- x row norms from Xs (row = tid>>2, c-chunk = (tid&3)*32) ----
  {
    const int row = tid >> 2, cq = tid & 3;
    float s = 0.f;
    #pragma unroll
    for (int o = 0; o < 4; ++o) {
      const int oct = cq * 4 + o;
      const short8v v = *(const short8v*)&Xs[row * 128 + ((oct ^ (row & 7)) << 3)];
      #pragma unroll
      for (int e = 0; e < 8; ++e) {
        const float xe = bf2f((unsigned short)v[e]);
        s = fmaf(xe, xe, s);
      }
    }
    s += __shfl_xor(s, 1);
    s += __shfl_xor(s, 2);
    if ((tid & 3) == 0) G[row * GSTR + 24] = s;
  }

  // ---- MFMA K-loop: wave = m-tile (16 rows), 2 n-tiles, 4 k-steps ----
  {
    const int arow = wave * 16 + (lane & 15);
    const int q0   = lane & 15;
    f32x4 acc0 = {0.f, 0.f, 0.f, 0.f}, acc1 = {0.f, 0.f, 0.f, 0.f};
    #pragma unroll
    for (int kk = 0; kk < 4; ++kk) {
      const int oct = kk * 4 + (lane >> 4);
      const short8v a  = *(const short8v*)&Xs[arow * 128 + ((oct ^ (arow & 7)) << 3)];
      const short8v b0 = *(const short8v*)&Wb[q0 * 128 + ((oct ^ (q0 & 7)) << 3)];
      const short8v b1 = *(const short8v*)&Wb[(q0 + 16) * 128 + ((oct ^ ((q0 + 16) & 7)) << 3)];
      acc0 = __builtin_amdgcn_mfma_f32_16x16x32_bf16(a, b0, acc0, 0, 0, 0);
      acc1 = __builtin_amdgcn_mfma_f32_16x16x32_bf16(a, b1, acc1, 0, 0, 0);
    }
    // C/D: col = lane&15, row = (lane>>4)*4 + reg  [m89]
    const int col = lane & 15, rq = (lane >> 4) * 4;
    #pragma unroll
    for (int r = 0; r < 4; ++r)
      G[(wave * 16 + rq + r) * GSTR + col] = acc0[r];
    if (col < 8) {
      #pragma unroll
      for (int r = 0; r < 4; ++r)
        G[(wave * 16 + rq + r) * GSTR + 16 + col] = acc1[r];
    }
  }
  __syncthreads();

  // ---- phase 2: one (p, f) output per thread-iteration ----
  for (int o = tid; o < TT * 8; o += 256) {
    const int pl = o >> 3, f = o & 7;
    const int p  = p0 + pl;

    float xn[3], dots[3][3];
    #pragma unroll
    for (int i = 0; i < 3; ++i) {
      xn[i] = G[(pl + i) * GSTR + 24];
      #pragma unroll
      for (int j = 0; j < 3; ++j) dots[i][j] = G[(pl + i) * GSTR + j * 8 + f];
    }

    float D[3][3];
    #pragma unroll
    for (int i = 0; i < 3; ++i) {
      #pragma unroll
      for (int j = 0; j < 3; ++j) {
        const float sq = xn[i] + WN[j * 8 + f] - 2.f * dots[i][j];
        D[i][j] = sqrtf(fmaxf(sq, 0.f));
      }
    }

    float cost[4][4];
    cost[0][0] = 0.f;  cost[0][1] = BIGV; cost[0][2] = BIGV; cost[0][3] = BIGV;
    #pragma unroll
    for (int i = 1; i <= 3; ++i) {
      cost[i][0] = BIGV;
      #pragma unroll
      for (int j = 1; j <= 3; ++j) {
        cost[i][j] = D[i-1][j-1] +
            fminf(fminf(cost[i][j-1], cost[i-1][j-1]), cost[i-1][j]);
      }
    }

    float acc2 = dots[2][2];
    {
      float acc = acc2;
      int st = (3 << 2) | 3;
      bool active = true;
      #pragma unroll 1
      for (int s = 0; s < 5; ++s) {
        if (!active) break;
        switch (st) {
          TRACE_CASE(1, 1)
          TRACE_CASE(1, 2)
          TRACE_CASE(1, 3)
          TRACE_CASE(2, 1)
          TRACE_CASE(2, 2)
          TRACE_CASE(2, 3)
          TRACE_CASE(3, 1)
          TRACE_CASE(3, 2)
          TRACE_CASE(3, 3)
          default: active = false; break;
        }
      }
      acc2 = acc;
    }

    out[((size_t)b * P + p) * 8 + f] = fmaxf(acc2 + BI[f], 0.f);
  }
}

extern "C" void kernel_launch(void* const* d_in, const int* in_sizes, int n_in,
                              void* d_out, int out_size, void* d_ws, size_t ws_size,
                              hipStream_t stream) {
  const float* x    = (const float*)d_in[0];
  const float* w    = (const float*)d_in[1];
  const float* bias = (const float*)d_in[2];
  float* out        = (float*)d_out;

  dim3 grid(33, 32);  // 33*62 = 2046 positions
  dwa_cnn_kernel<<<grid, 256, 0, stream>>>(x, w, bias, out);
}